// Round 1
// baseline (3829.239 us; speedup 1.0000x reference)
//
#include <hip/hip_runtime.h>

// Problem constants (B,S,H,NH,P) = (2,2048,1024,16,64)
#define B_ 2
#define S_ 2048
#define H_ 1024
#define NH_ 16
#define P_ 64

// XOR swizzle at float4 granularity, keyed on row>>2 so that reads whose rows
// are 4 apart (4*ty+i / 4*tx+j patterns) land in distinct bank groups.
static __device__ __forceinline__ int swz64(int row, int p) {
  return row * 64 + ((((p >> 2) ^ (row >> 2)) & 15) << 2) + (p & 3);
}
static __device__ __forceinline__ int swz32(int row, int p) {
  return row * 32 + ((((p >> 2) ^ (row >> 2)) & 7) << 2) + (p & 3);
}

static __device__ __forceinline__ void fma4(float (&acc)[4], float s, const float4& v) {
  acc[0] += s * v.x; acc[1] += s * v.y; acc[2] += s * v.z; acc[3] += s * v.w;
}

// ---------------------------------------------------------------------------
// Kernel 1: QKV projection.  out_t[b][n][s][p] = sum_h x[b][s][h] * W[n][t][h][p]
// grid = B*NH*3*(S/64), block 256, tile 64(rows s) x 64(p), BK=32
// ---------------------------------------------------------------------------
__global__ __launch_bounds__(256) void qkv_kernel(
    const float* __restrict__ x, const float* __restrict__ W,
    float* __restrict__ Kb, float* __restrict__ Vb, float* __restrict__ Qb)
{
  __shared__ __align__(16) float As[64 * 32];  // x tile, row-major [s][k], swizzled
  __shared__ __align__(16) float Bs[32 * 64];  // W tile, k-major [k][p], linear

  int blk = blockIdx.x;
  const int it = blk & 31; blk >>= 5;
  const int t  = blk % 3;  blk /= 3;
  const int n  = blk & 15;
  const int b  = blk >> 4;
  const int s0 = it * 64;
  const int tid = threadIdx.x;
  const int tx = tid & 15, ty = tid >> 4;
  const int arow = tid >> 3, af = tid & 7;

  const float* Asrc = x + ((size_t)b * S_ + s0) * H_;
  const float* Bsrc = W + ((size_t)n * 3 + t) * H_ * P_;

  float acc[4][4] = {};

  for (int k0 = 0; k0 < H_; k0 += 32) {
    #pragma unroll
    for (int r = 0; r < 2; ++r) {
      int rr = arow + r * 32;
      *(float4*)&As[swz32(rr, af * 4)] =
          *(const float4*)(Asrc + (size_t)rr * H_ + k0 + af * 4);
    }
    #pragma unroll
    for (int r = 0; r < 2; ++r) {
      int idx4 = tid + r * 256;
      *(float4*)&Bs[idx4 * 4] = *(const float4*)(Bsrc + (size_t)k0 * P_ + idx4 * 4);
    }
    __syncthreads();
    #pragma unroll
    for (int k4 = 0; k4 < 8; ++k4) {
      float4 a[4], bq[4];
      #pragma unroll
      for (int i = 0; i < 4; ++i) a[i] = *(const float4*)&As[swz32(ty * 4 + i, k4 * 4)];
      #pragma unroll
      for (int q = 0; q < 4; ++q) bq[q] = *(const float4*)&Bs[(k4 * 4 + q) * 64 + tx * 4];
      #pragma unroll
      for (int i = 0; i < 4; ++i) {
        fma4(acc[i], a[i].x, bq[0]);
        fma4(acc[i], a[i].y, bq[1]);
        fma4(acc[i], a[i].z, bq[2]);
        fma4(acc[i], a[i].w, bq[3]);
      }
    }
    __syncthreads();
  }

  float* dstb = (t == 0) ? Kb : ((t == 1) ? Vb : Qb);
  float* dst = dstb + (((size_t)b * NH_ + n) * S_ + s0) * P_;
  #pragma unroll
  for (int i = 0; i < 4; ++i) {
    float4 v = make_float4(acc[i][0], acc[i][1], acc[i][2], acc[i][3]);
    *(float4*)(dst + (size_t)(ty * 4 + i) * P_ + tx * 4) = v;
  }
}

// ---------------------------------------------------------------------------
// Kernel 2: per-column (over i) online max / sum-exp of scores[i,j]=K_i·Q_j/8.
// One block per (b, n, j-tile of 64). Iterates all i-tiles.
// ---------------------------------------------------------------------------
__global__ __launch_bounds__(256) void stats_kernel(
    const float* __restrict__ Kb, const float* __restrict__ Qb,
    float* __restrict__ cmax, float* __restrict__ csum)
{
  __shared__ __align__(16) float Qs[64 * 64];
  __shared__ __align__(16) float Ks[64 * 64];
  __shared__ __align__(16) float Ss[64 * 64];
  __shared__ float red[4 * 64];
  __shared__ float cm[64], cz[64], mn[64];

  int blk = blockIdx.x;
  const int jt = blk & 31; blk >>= 5;
  const int n = blk & 15;
  const int b = blk >> 4;
  const int tid = threadIdx.x;
  const int tx = tid & 15, ty = tid >> 4;
  const size_t bn = (size_t)b * NH_ + n;
  const int j0 = jt * 64;

  {
    const float* src = Qb + (bn * S_ + j0) * P_;
    #pragma unroll
    for (int r = 0; r < 4; ++r) {
      int idx4 = tid + r * 256;
      int row = idx4 >> 4, p0 = (idx4 & 15) << 2;
      *(float4*)&Qs[swz64(row, p0)] = *(const float4*)(src + row * P_ + p0);
    }
  }
  if (tid < 64) { cm[tid] = -3.0e38f; cz[tid] = 0.0f; }
  __syncthreads();

  const int qq = tid >> 6;   // 0..3 : row-quarter for reduction
  const int jc = tid & 63;   // column

  for (int i0 = 0; i0 < S_; i0 += 64) {
    {
      const float* src = Kb + (bn * S_ + i0) * P_;
      #pragma unroll
      for (int r = 0; r < 4; ++r) {
        int idx4 = tid + r * 256;
        int row = idx4 >> 4, p0 = (idx4 & 15) << 2;
        *(float4*)&Ks[swz64(row, p0)] = *(const float4*)(src + row * P_ + p0);
      }
    }
    __syncthreads();

    float sc[4][4] = {};
    #pragma unroll
    for (int p4 = 0; p4 < 16; ++p4) {
      float4 ka[4], qa[4];
      #pragma unroll
      for (int i = 0; i < 4; ++i) ka[i] = *(const float4*)&Ks[swz64(ty * 4 + i, p4 * 4)];
      #pragma unroll
      for (int j = 0; j < 4; ++j) qa[j] = *(const float4*)&Qs[swz64(tx * 4 + j, p4 * 4)];
      #pragma unroll
      for (int i = 0; i < 4; ++i) {
        #pragma unroll
        for (int j = 0; j < 4; ++j) {
          sc[i][j] += ka[i].x * qa[j].x;
          sc[i][j] += ka[i].y * qa[j].y;
          sc[i][j] += ka[i].z * qa[j].z;
          sc[i][j] += ka[i].w * qa[j].w;
        }
      }
    }
    #pragma unroll
    for (int i = 0; i < 4; ++i) {
      float4 v = make_float4(sc[i][0] * 0.125f, sc[i][1] * 0.125f,
                             sc[i][2] * 0.125f, sc[i][3] * 0.125f);
      *(float4*)&Ss[(ty * 4 + i) * 64 + tx * 4] = v;
    }
    __syncthreads();

    float lm = -3.0e38f;
    #pragma unroll
    for (int r = 0; r < 16; ++r) lm = fmaxf(lm, Ss[(qq * 16 + r) * 64 + jc]);
    red[qq * 64 + jc] = lm;
    __syncthreads();
    if (tid < 64) {
      float m4 = fmaxf(fmaxf(red[tid], red[64 + tid]),
                       fmaxf(red[128 + tid], red[192 + tid]));
      mn[tid] = fmaxf(cm[tid], m4);
    }
    __syncthreads();
    const float mj = mn[jc];
    float ls = 0.0f;
    #pragma unroll
    for (int r = 0; r < 16; ++r) ls += __expf(Ss[(qq * 16 + r) * 64 + jc] - mj);
    red[qq * 64 + jc] = ls;
    __syncthreads();
    if (tid < 64) {
      float ts = red[tid] + red[64 + tid] + red[128 + tid] + red[192 + tid];
      cz[tid] = cz[tid] * __expf(cm[tid] - mn[tid]) + ts;
      cm[tid] = mn[tid];
    }
    __syncthreads();
  }
  if (tid < 64) {
    cmax[bn * S_ + j0 + tid] = cm[tid];
    csum[bn * S_ + j0 + tid] = cz[tid];
  }
}

// ---------------------------------------------------------------------------
// Kernel 3: out[i,:] = sum_j w[i,j] * V[j,:];  w = exp(s-m_j)/Z_j or 1/S (masked).
// One block per (b, n, i-tile of 64); writes hidden in [B][S][H] layout.
// ---------------------------------------------------------------------------
__global__ __launch_bounds__(256) void av_kernel(
    const float* __restrict__ Kb, const float* __restrict__ Qb,
    const float* __restrict__ Vb,
    const float* __restrict__ cmax, const float* __restrict__ csum,
    const int* __restrict__ mask, float* __restrict__ hid)
{
  __shared__ __align__(16) float Ks[64 * 64];
  __shared__ __align__(16) float QWs[64 * 64];   // Q tile, reused as W tile
  __shared__ __align__(16) float Vs[64 * 64];    // k-major [j][p], linear
  __shared__ float ms[64], zi[64];
  __shared__ int mk[64];

  int blk = blockIdx.x;
  const int it = blk & 31; blk >>= 5;
  const int n = blk & 15;
  const int b = blk >> 4;
  const int tid = threadIdx.x;
  const int tx = tid & 15, ty = tid >> 4;
  const size_t bn = (size_t)b * NH_ + n;
  const int i0 = it * 64;

  {
    const float* src = Kb + (bn * S_ + i0) * P_;
    #pragma unroll
    for (int r = 0; r < 4; ++r) {
      int idx4 = tid + r * 256;
      int row = idx4 >> 4, p0 = (idx4 & 15) << 2;
      *(float4*)&Ks[swz64(row, p0)] = *(const float4*)(src + row * P_ + p0);
    }
  }
  float out[4][4] = {};

  for (int j0 = 0; j0 < S_; j0 += 64) {
    __syncthreads();  // previous PV reads (and initial Ks staging) complete
    {
      const float* qsrc = Qb + (bn * S_ + j0) * P_;
      const float* vsrc = Vb + (bn * S_ + j0) * P_;
      #pragma unroll
      for (int r = 0; r < 4; ++r) {
        int idx4 = tid + r * 256;
        int row = idx4 >> 4, p0 = (idx4 & 15) << 2;
        *(float4*)&QWs[swz64(row, p0)] = *(const float4*)(qsrc + row * P_ + p0);
        *(float4*)&Vs[row * 64 + p0]   = *(const float4*)(vsrc + row * P_ + p0);
      }
      if (tid < 64) {
        ms[tid] = cmax[bn * S_ + j0 + tid];
        zi[tid] = 1.0f / csum[bn * S_ + j0 + tid];
        mk[tid] = mask[(size_t)b * S_ + j0 + tid];
      }
    }
    __syncthreads();

    float sc[4][4] = {};
    #pragma unroll
    for (int p4 = 0; p4 < 16; ++p4) {
      float4 ka[4], qa[4];
      #pragma unroll
      for (int i = 0; i < 4; ++i) ka[i] = *(const float4*)&Ks[swz64(ty * 4 + i, p4 * 4)];
      #pragma unroll
      for (int j = 0; j < 4; ++j) qa[j] = *(const float4*)&QWs[swz64(tx * 4 + j, p4 * 4)];
      #pragma unroll
      for (int i = 0; i < 4; ++i) {
        #pragma unroll
        for (int j = 0; j < 4; ++j) {
          sc[i][j] += ka[i].x * qa[j].x;
          sc[i][j] += ka[i].y * qa[j].y;
          sc[i][j] += ka[i].z * qa[j].z;
          sc[i][j] += ka[i].w * qa[j].w;
        }
      }
    }
    float wv[4][4];
    #pragma unroll
    for (int i = 0; i < 4; ++i) {
      #pragma unroll
      for (int j = 0; j < 4; ++j) {
        int jj = tx * 4 + j;
        float s = sc[i][j] * 0.125f;
        wv[i][j] = mk[jj] ? (__expf(s - ms[jj]) * zi[jj]) : (1.0f / 2048.0f);
      }
    }
    __syncthreads();  // all Q reads of QWs done before overwrite
    #pragma unroll
    for (int i = 0; i < 4; ++i) {
      float4 v = make_float4(wv[i][0], wv[i][1], wv[i][2], wv[i][3]);
      *(float4*)&QWs[swz64(ty * 4 + i, tx * 4)] = v;
    }
    __syncthreads();

    #pragma unroll
    for (int j4 = 0; j4 < 16; ++j4) {
      float4 wa[4], vv[4];
      #pragma unroll
      for (int i = 0; i < 4; ++i) wa[i] = *(const float4*)&QWs[swz64(ty * 4 + i, j4 * 4)];
      #pragma unroll
      for (int q = 0; q < 4; ++q) vv[q] = *(const float4*)&Vs[(j4 * 4 + q) * 64 + tx * 4];
      #pragma unroll
      for (int i = 0; i < 4; ++i) {
        fma4(out[i], wa[i].x, vv[0]);
        fma4(out[i], wa[i].y, vv[1]);
        fma4(out[i], wa[i].z, vv[2]);
        fma4(out[i], wa[i].w, vv[3]);
      }
    }
  }

  float* dst = hid + ((size_t)b * S_ + i0) * H_ + n * 64;
  #pragma unroll
  for (int i = 0; i < 4; ++i) {
    float4 v = make_float4(out[i][0], out[i][1], out[i][2], out[i][3]);
    *(float4*)(dst + (size_t)(ty * 4 + i) * H_ + tx * 4) = v;
  }
}

// ---------------------------------------------------------------------------
// Kernel 4: out = hidden @ Wl.T + bl.   grid = (B*S/64)*(H/64)
// ---------------------------------------------------------------------------
__global__ __launch_bounds__(256) void final_kernel(
    const float* __restrict__ hid, const float* __restrict__ Wl,
    const float* __restrict__ bl, float* __restrict__ out)
{
  __shared__ __align__(16) float As[64 * 32];
  __shared__ __align__(16) float Bs[64 * 32];  // Wl rows (o), row-major over k
  int blk = blockIdx.x;
  const int ot = blk & 15;
  const int rt = blk >> 4;
  const int r0 = rt * 64, o0 = ot * 64;
  const int tid = threadIdx.x;
  const int tx = tid & 15, ty = tid >> 4;
  const int arow = tid >> 3, af = tid & 7;

  float acc[4][4] = {};
  for (int k0 = 0; k0 < H_; k0 += 32) {
    #pragma unroll
    for (int r = 0; r < 2; ++r) {
      int rr = arow + r * 32;
      *(float4*)&As[swz32(rr, af * 4)] =
          *(const float4*)(hid + (size_t)(r0 + rr) * H_ + k0 + af * 4);
      *(float4*)&Bs[swz32(rr, af * 4)] =
          *(const float4*)(Wl + (size_t)(o0 + rr) * H_ + k0 + af * 4);
    }
    __syncthreads();
    #pragma unroll
    for (int k4 = 0; k4 < 8; ++k4) {
      float4 a[4], w[4];
      #pragma unroll
      for (int i = 0; i < 4; ++i) a[i] = *(const float4*)&As[swz32(ty * 4 + i, k4 * 4)];
      #pragma unroll
      for (int j = 0; j < 4; ++j) w[j] = *(const float4*)&Bs[swz32(tx * 4 + j, k4 * 4)];
      #pragma unroll
      for (int i = 0; i < 4; ++i) {
        #pragma unroll
        for (int j = 0; j < 4; ++j) {
          acc[i][j] += a[i].x * w[j].x;
          acc[i][j] += a[i].y * w[j].y;
          acc[i][j] += a[i].z * w[j].z;
          acc[i][j] += a[i].w * w[j].w;
        }
      }
    }
    __syncthreads();
  }
  const float4 bv = *(const float4*)(bl + o0 + tx * 4);
  #pragma unroll
  for (int i = 0; i < 4; ++i) {
    float4 v = make_float4(acc[i][0] + bv.x, acc[i][1] + bv.y,
                           acc[i][2] + bv.z, acc[i][3] + bv.w);
    *(float4*)(out + (size_t)(r0 + ty * 4 + i) * H_ + o0 + tx * 4) = v;
  }
}

// ---------------------------------------------------------------------------
extern "C" void kernel_launch(void* const* d_in, const int* in_sizes, int n_in,
                              void* d_out, int out_size, void* d_ws, size_t ws_size,
                              hipStream_t stream) {
  const float* x    = (const float*)d_in[0];
  const int*   mask = (const int*)d_in[1];
  const float* W    = (const float*)d_in[2];
  const float* Wl   = (const float*)d_in[3];
  const float* bl   = (const float*)d_in[4];
  float* out = (float*)d_out;

  // Workspace carve-up (floats): K,V,Q [B][NH][S][P]; col stats; hidden [B][S][H]
  const size_t SZ_KVQ = (size_t)B_ * NH_ * S_ * P_;   // 4,194,304
  const size_t SZ_COL = (size_t)B_ * NH_ * S_;        // 65,536
  float* ws = (float*)d_ws;
  float* Kb   = ws;
  float* Vb   = Kb + SZ_KVQ;
  float* Qb   = Vb + SZ_KVQ;
  float* cmax = Qb + SZ_KVQ;
  float* csum = cmax + SZ_COL;
  float* hid  = csum + SZ_COL;
  // total = 3*SZ_KVQ + 2*SZ_COL + B*S*H floats ~= 67.6 MB

  qkv_kernel  <<<B_ * NH_ * 3 * (S_ / 64), 256, 0, stream>>>(x, W, Kb, Vb, Qb);
  stats_kernel<<<B_ * NH_ * (S_ / 64),     256, 0, stream>>>(Kb, Qb, cmax, csum);
  av_kernel   <<<B_ * NH_ * (S_ / 64),     256, 0, stream>>>(Kb, Qb, Vb, cmax, csum, mask, hid);
  final_kernel<<<(B_ * S_ / 64) * (H_ / 64), 256, 0, stream>>>(hid, Wl, bl, out);
}